// Round 9
// baseline (459.142 us; speedup 1.0000x reference)
//
#include <hip/hip_runtime.h>
#include <stdint.h>

#define SEQ 4096
#define HID 2048

typedef __attribute__((ext_vector_type(8))) short short8;
typedef __attribute__((ext_vector_type(8))) _Float16 half8;
typedef __attribute__((ext_vector_type(4))) float f32x4;
typedef __attribute__((ext_vector_type(16))) float f32x16;
typedef unsigned int u32;
typedef __attribute__((ext_vector_type(4))) u32 u32x4;

__device__ __forceinline__ short bf16_rne(float f) {
  u32 u = __builtin_bit_cast(u32, f);
  u += 0x7FFFu + ((u >> 16) & 1u);
  return (short)(u >> 16);
}

__device__ __forceinline__ void gload16(const void* gp, void* lp) {
  __builtin_amdgcn_global_load_lds(
      (const __attribute__((address_space(1))) u32*)(uintptr_t)gp,
      (__attribute__((address_space(3))) u32*)(uintptr_t)lp, 16, 0, 0);
}

// ---------------- cast fp32 -> bf16 (8 elems/thread) ----------------
__global__ __launch_bounds__(256) void cast_bf16(const float* __restrict__ in,
                                                 short* __restrict__ out, int n8) {
  int i = blockIdx.x * 256 + threadIdx.x;
  if (i >= n8) return;
  const f32x4* p = (const f32x4*)in + (size_t)i * 2;
  f32x4 a = p[0], b = p[1];
  short8 o;
#pragma unroll
  for (int j = 0; j < 4; ++j) { o[j] = bf16_rne(a[j]); o[j + 4] = bf16_rne(b[j]); }
  *((short8*)out + i) = o;
}

// ---------------- transpose V with per-16 t-bit-swap (bits 2<->3) ----------------
// vt[d][pos] = V[t = (pos & ~15) | (pos&3) | ((pos&4)<<1) | ((pos&8)>>1)][d]
// This k-order permutation lets the attn PV MFMA consume each lane's OWN P words
// (no cross-half routing): slot s needs t=perm16(s), and perm16 is an involution.
__global__ __launch_bounds__(256) void transpose_v(const short* __restrict__ qkv,
                                                   short* __restrict__ vt) {
  __shared__ __align__(16) short tile[64][72];
  int rb = blockIdx.x * 64, cb = blockIdx.y * 64;
  int tid = threadIdx.x;
  int tr = tid >> 3, tc = (tid & 7) * 8;
#pragma unroll
  for (int i = 0; i < 2; ++i)
    *(short8*)&tile[tr + i * 32][tc] =
        *(const short8*)&qkv[(size_t)(rb + tr + i * 32) * 3072 + 2560 + cb + tc];
  __syncthreads();
#pragma unroll
  for (int i = 0; i < 2; ++i) {
    int c = tr + i * 32;
    short8 v;
#pragma unroll
    for (int j = 0; j < 8; ++j) {
      int pos = tc + j;
      int tl = (pos & ~15) | (pos & 3) | ((pos & 4) << 1) | ((pos & 8) >> 1);
      v[j] = tile[tl][c];
    }
    *(short8*)&vt[(size_t)(cb + c) * SEQ + rb + tc] = v;
  }
}

// ---------------- GEMM NT: C[m,n] = sum_k A[m,k]*B[n,k] ----------------
template <typename CT>
__global__ __launch_bounds__(256, 2) void gemm_nt(const short* __restrict__ A,
                                                  const short* __restrict__ B,
                                                  CT* __restrict__ C, int M, int N, int K) {
  __shared__ __align__(16) short As[128 * 32];
  __shared__ __align__(16) short Bs[128 * 32];
  int tid = threadIdx.x, wave = tid >> 6, lane = tid & 63;
  int lr = lane & 15, lg = lane >> 4;
  int wr = wave >> 1, wc = wave & 1;
  size_t rowA0 = (size_t)blockIdx.y * 128, colB0 = (size_t)blockIdx.x * 128;
  f32x4 acc[4][4] = {};

  for (int kt = 0; kt < K; kt += 32) {
#pragma unroll
    for (int c = 0; c < 2; ++c) {
      int chunk = wave * 2 + c;
      int row = chunk * 16 + (lane >> 2);
      int col = (lane & 3) * 8;
      gload16(A + (rowA0 + row) * (size_t)K + kt + col, &As[chunk * 512]);
      gload16(B + (colB0 + row) * (size_t)K + kt + col, &Bs[chunk * 512]);
    }
    __syncthreads();
    short8 a[4], b[4];
#pragma unroll
    for (int i = 0; i < 4; ++i) {
      a[i] = *(const short8*)&As[(wr * 64 + i * 16 + lr) * 32 + lg * 8];
      b[i] = *(const short8*)&Bs[(wc * 64 + i * 16 + lr) * 32 + lg * 8];
    }
#pragma unroll
    for (int i = 0; i < 4; ++i)
#pragma unroll
      for (int j = 0; j < 4; ++j)
        acc[i][j] = __builtin_amdgcn_mfma_f32_16x16x32_bf16(a[i], b[j], acc[i][j], 0, 0, 0);
    __syncthreads();
  }
#pragma unroll
  for (int i = 0; i < 4; ++i)
#pragma unroll
    for (int j = 0; j < 4; ++j)
#pragma unroll
      for (int r = 0; r < 4; ++r) {
        size_t row = rowA0 + wr * 64 + i * 16 + lg * 4 + r;
        size_t col = colB0 + wc * 64 + j * 16 + lr;
        if constexpr (sizeof(CT) == 2) C[row * N + col] = (CT)bf16_rne(acc[i][j][r]);
        else C[row * N + col] = acc[i][j][r];
      }
}

// ---------------- flash attention: 32x32 MFMA, swapped QK, zero-routing PV ----------
// Per wave: 32 q-rows, D=128. Block = 4 waves (128 q). KVBLK=32, dbuf, 1 barrier/iter.
// K LDS granule (dg,t): byte=(dg*32+t)*16 holds K[t][dg*8..+7]  (8 KB/buf)
// V LDS granule (tg,p): byte=(tg*128+d)*16 holds Vt'[d][tg*8..+7] (8 KB/buf, t-permuted)
// All fragment reads: 32-lane sequential 512B runs -> conflict-free (r8: 0 conflicts).
// NSPLIT=2: blockIdx.z = KV half; fp16 unnormalized partials + fp32 m/l; 4 blocks/CU.
template <int NSPLIT>
__global__ __launch_bounds__(256, 4) void attn_kernel(const short* __restrict__ QKV,
                                                      const short* __restrict__ Vt,
                                                      short* __restrict__ Oat,
                                                      _Float16* __restrict__ Op,
                                                      float* __restrict__ ml) {
  __shared__ __align__(16) short Ks[2][4096];
  __shared__ __align__(16) short Vs[2][4096];
  int tid = threadIdx.x, wave = tid >> 6, lane = tid & 63;
  int l31 = lane & 31, hi = lane >> 5;
  int h = blockIdx.y, kv = h >> 2;
  int part = (NSPLIT == 2) ? blockIdx.z : 0;
  int q0 = blockIdx.x * 128 + wave * 32;

  // Q B-fragments: qf[kb] = Q[q0+l31][d = kb*16 + hi*8 + 0..7]
  short8 qf[8];
#pragma unroll
  for (int kb = 0; kb < 8; ++kb)
    qf[kb] = *(const short8*)&QKV[(size_t)(q0 + l31) * 3072 + h * 128 + kb * 16 + hi * 8];

  f32x16 oacc[4] = {};
  float m_run = -1e30f, lsum = 0.f;

  const float sc = 1.44269504089f * 0.08838834764831845f;  // log2e / sqrt(128)
  const float THR_S = 60.f;
  const short* Kbase = QKV + 2048 + kv * 128;

  auto stageK = [&](int b, int t0) {
#pragma unroll
    for (int cc = 0; cc < 2; ++cc) {
      int c = wave * 2 + cc;  // granule: dg = 2c + hi, t = l31
      gload16(Kbase + (size_t)(t0 + l31) * 3072 + c * 16 + hi * 8, &Ks[b][c * 512]);
    }
  };
  auto stageV = [&](int b, int t0) {
#pragma unroll
    for (int cc = 0; cc < 2; ++cc) {
      int c = wave * 2 + cc;  // granule: tg = c>>1, d = (c&1)*64 + lane
      int d = (c & 1) * 64 + lane;
      gload16(Vt + (size_t)(kv * 128 + d) * SEQ + t0 + (c >> 1) * 8, &Vs[b][c * 512]);
    }
  };

  const int tbeg = part * (SEQ / NSPLIT);
  const int tend = tbeg + SEQ / NSPLIT;

  stageK(0, tbeg);
  stageV(0, tbeg);
  __syncthreads();
  int buf = 0;

  for (int t0 = tbeg; t0 < tend; t0 += 32) {
    int tn = (t0 + 32 < tend) ? t0 + 32 : tbeg;
    stageK(buf ^ 1, tn);
    stageV(buf ^ 1, tn);

    // S^T = mfma(K, Q): col = q = l31; reg r -> t = (r&3)+8*(r>>2)+4*hi
    f32x16 sacc = {};
    __builtin_amdgcn_s_setprio(1);
#pragma unroll
    for (int kb = 0; kb < 8; ++kb) {
      short8 kf = *(const short8*)&Ks[buf][((kb * 2 + hi) * 32 + l31) * 8];
      sacc = __builtin_amdgcn_mfma_f32_32x32x16_bf16(kf, qf[kb], sacc, 0, 0, 0);
    }
    __builtin_amdgcn_s_setprio(0);

    // in-lane max over this lane's 16 t-values of row q=l31; rare full rescale
    float vmax = fmaxf(sacc[0], sacc[1]);
#pragma unroll
    for (int r = 2; r < 16; ++r) vmax = fmaxf(vmax, sacc[r]);
    if (__any(vmax > m_run + THR_S)) {
      float mnew = fmaxf(fmaxf(vmax, __shfl_xor(vmax, 32)), m_run);
      float corr = __builtin_amdgcn_exp2f((m_run - mnew) * sc);
      lsum *= corr;
      m_run = mnew;
#pragma unroll
      for (int nb = 0; nb < 4; ++nb) oacc[nb] *= corr;
    }

    // P = exp(S - m): fused exp + sum + pack, no p[] array, no cross-half routing
    float msc = m_run * sc;
    float ps = 0.f;
    u32 w[8];
#pragma unroll
    for (int i = 0; i < 8; ++i) {
      float p0 = __builtin_amdgcn_exp2f(sacc[2 * i] * sc - msc);
      float p1 = __builtin_amdgcn_exp2f(sacc[2 * i + 1] * sc - msc);
      ps += p0 + p1;
      asm("v_cvt_pk_bf16_f32 %0, %1, %2" : "=v"(w[i]) : "v"(p0), "v"(p1));
    }
    lsum += ps;
    short8 pa0 = __builtin_bit_cast(short8, (u32x4){w[0], w[1], w[2], w[3]});
    short8 pa1 = __builtin_bit_cast(short8, (u32x4){w[4], w[5], w[6], w[7]});

    // PV: O[q][d] += P[q][t] V[t][d]; V staged in perm16 t-order so A = own words
    __builtin_amdgcn_s_setprio(1);
#pragma unroll
    for (int nb = 0; nb < 4; ++nb) {
      short8 v0 = *(const short8*)&Vs[buf][((hi)*128 + nb * 32 + l31) * 8];
      oacc[nb] = __builtin_amdgcn_mfma_f32_32x32x16_bf16(pa0, v0, oacc[nb], 0, 0, 0);
      short8 v1 = *(const short8*)&Vs[buf][((2 + hi) * 128 + nb * 32 + l31) * 8];
      oacc[nb] = __builtin_amdgcn_mfma_f32_32x32x16_bf16(pa1, v1, oacc[nb], 0, 0, 0);
    }
    __builtin_amdgcn_s_setprio(0);

    __syncthreads();  // next buffer staged; all waves done reading buf
    buf ^= 1;
  }

  lsum += __shfl_xor(lsum, 32);  // full row sum for q = l31

  if constexpr (NSPLIT == 1) {
    float linv = 1.f / lsum;
#pragma unroll
    for (int r = 0; r < 16; ++r) {
      int qrow = (r & 3) + 8 * (r >> 2) + 4 * hi;
      float lr_ = __shfl(linv, qrow);
#pragma unroll
      for (int nb = 0; nb < 4; ++nb)
        Oat[(size_t)(q0 + qrow) * HID + h * 128 + nb * 32 + l31] = bf16_rne(oacc[nb][r] * lr_);
    }
  } else {
    _Float16* Obase = Op + (size_t)part * SEQ * HID;
#pragma unroll
    for (int r = 0; r < 16; ++r) {
      int qrow = (r & 3) + 8 * (r >> 2) + 4 * hi;
#pragma unroll
      for (int nb = 0; nb < 4; ++nb)
        Obase[(size_t)(q0 + qrow) * HID + h * 128 + nb * 32 + l31] = (_Float16)oacc[nb][r];
    }
    if (hi == 0) {
      size_t base = (((size_t)part * SEQ + q0 + l31) * 16 + h) * 2;
      ml[base] = m_run;
      ml[base + 1] = lsum;
    }
  }
}

// ---------------- merge two KV partitions ----------------
__global__ __launch_bounds__(256) void merge_parts(const _Float16* __restrict__ Op,
                                                   const float* __restrict__ ml,
                                                   short* __restrict__ Oat) {
  const float sc = 1.44269504089f * 0.08838834764831845f;
  int i = blockIdx.x * 256 + threadIdx.x;
  int row = i >> 8;
  int col = (i & 255) * 8;
  int h = col >> 7;
  const float* a = ml + (((size_t)row) * 16 + h) * 2;
  const float* b = ml + (((size_t)SEQ + row) * 16 + h) * 2;
  float m1 = a[0], l1 = a[1], m2 = b[0], l2 = b[1];
  float M = fmaxf(m1, m2);
  float e1 = __builtin_amdgcn_exp2f((m1 - M) * sc);
  float e2 = __builtin_amdgcn_exp2f((m2 - M) * sc);
  float inv = 1.f / (l1 * e1 + l2 * e2);
  half8 o1 = *(const half8*)&Op[(size_t)row * HID + col];
  half8 o2 = *(const half8*)&Op[(size_t)SEQ * HID + (size_t)row * HID + col];
  short8 o;
#pragma unroll
  for (int j = 0; j < 8; ++j)
    o[j] = bf16_rne(((float)o1[j] * e1 + (float)o2[j] * e2) * inv);
  *(short8*)&Oat[(size_t)row * HID + col] = o;
}

extern "C" void kernel_launch(void* const* d_in, const int* in_sizes, int n_in,
                              void* d_out, int out_size, void* d_ws, size_t ws_size,
                              hipStream_t stream) {
  const float* x = (const float*)d_in[0];
  const float* Wq = (const float*)d_in[1];
  const float* Wk = (const float*)d_in[2];
  const float* Wv = (const float*)d_in[3];
  const float* Wo = (const float*)d_in[4];
  float* out = (float*)d_out;
  char* ws = (char*)d_ws;

  // workspace layout:
  short* xb = (short*)(ws);                          // [4096][2048]  16MB (later: Oat)
  short* wqkv = (short*)(ws + (16u << 20));          // [3072][2048]  12MB (later: Vt)
  short* wob = (short*)(ws + (28u << 20));           // [2048][2048]   8MB
  short* qkv = (short*)(ws + (36u << 20));           // [4096][3072]  24MB
  short* vt = wqkv;                                  // [512][4096]    4MB
  short* oat = xb;                                   // [4096][2048]  16MB
  _Float16* opart = (_Float16*)(ws + 62914560u);     // [2][4096][2048] fp16 32MB
  float* mlb = (float*)(ws + 62914560u + 33554432u); // [2][4096][16][2] 1MB
  const bool split = ws_size >= (size_t)(62914560u + 33554432u + 1048576u);

  cast_bf16<<<4096, 256, 0, stream>>>(x, xb, 1048576);
  cast_bf16<<<2048, 256, 0, stream>>>(Wq, wqkv, 524288);
  cast_bf16<<<512, 256, 0, stream>>>(Wk, wqkv + (size_t)2048 * 2048, 131072);
  cast_bf16<<<512, 256, 0, stream>>>(Wv, wqkv + (size_t)2560 * 2048, 131072);
  cast_bf16<<<2048, 256, 0, stream>>>(Wo, wob, 524288);

  // QKV = x * [Wq;Wk;Wv]^T : [4096][3072]
  gemm_nt<short><<<dim3(24, 32), 256, 0, stream>>>(xb, wqkv, qkv, 4096, 3072, 2048);
  // V^T (t-bit-swapped) for the PV step
  transpose_v<<<dim3(64, 8), 256, 0, stream>>>(qkv, vt);
  // fused flash attention
  if (split) {
    attn_kernel<2><<<dim3(32, 16, 2), 256, 0, stream>>>(qkv, vt, nullptr, opart, mlb);
    merge_parts<<<4096, 256, 0, stream>>>(opart, mlb, oat);
  } else {
    attn_kernel<1><<<dim3(32, 16, 1), 256, 0, stream>>>(qkv, vt, oat, nullptr, nullptr);
  }
  // out = Oat * Wo^T (fp32 out)
  gemm_nt<float><<<dim3(16, 32), 256, 0, stream>>>(oat, wob, out, 4096, HID, 2048);
}

// Round 10
// 286.608 us; speedup vs baseline: 1.6020x; 1.6020x over previous
//
#include <hip/hip_runtime.h>
#include <stdint.h>

#define SEQ 4096
#define HID 2048

typedef __attribute__((ext_vector_type(8))) short short8;
typedef __attribute__((ext_vector_type(4))) float f32x4;
typedef __attribute__((ext_vector_type(16))) float f32x16;
typedef unsigned int u32;
typedef __attribute__((ext_vector_type(4))) u32 u32x4;

__device__ __forceinline__ short bf16_rne(float f) {
  u32 u = __builtin_bit_cast(u32, f);
  u += 0x7FFFu + ((u >> 16) & 1u);
  return (short)(u >> 16);
}

__device__ __forceinline__ void gload16(const void* gp, void* lp) {
  __builtin_amdgcn_global_load_lds(
      (const __attribute__((address_space(1))) u32*)(uintptr_t)gp,
      (__attribute__((address_space(3))) u32*)(uintptr_t)lp, 16, 0, 0);
}

// ---------------- cast fp32 -> bf16 (8 elems/thread) ----------------
__global__ __launch_bounds__(256) void cast_bf16(const float* __restrict__ in,
                                                 short* __restrict__ out, int n8) {
  int i = blockIdx.x * 256 + threadIdx.x;
  if (i >= n8) return;
  const f32x4* p = (const f32x4*)in + (size_t)i * 2;
  f32x4 a = p[0], b = p[1];
  short8 o;
#pragma unroll
  for (int j = 0; j < 4; ++j) { o[j] = bf16_rne(a[j]); o[j + 4] = bf16_rne(b[j]); }
  *((short8*)out + i) = o;
}

// ---------------- transpose V with per-16 t-bit-swap (bits 2<->3) ----------------
// vt[d][pos] = V[t = (pos & ~15) | (pos&3) | ((pos&4)<<1) | ((pos&8)>>1)][d]
// This k-order permutation lets the attn PV MFMA consume each lane's OWN P words
// (no cross-half routing): PV slot s needs t=perm16(s); perm16 is an involution.
__global__ __launch_bounds__(256) void transpose_v(const short* __restrict__ qkv,
                                                   short* __restrict__ vt) {
  __shared__ __align__(16) short tile[64][72];
  int rb = blockIdx.x * 64, cb = blockIdx.y * 64;
  int tid = threadIdx.x;
  int tr = tid >> 3, tc = (tid & 7) * 8;
#pragma unroll
  for (int i = 0; i < 2; ++i)
    *(short8*)&tile[tr + i * 32][tc] =
        *(const short8*)&qkv[(size_t)(rb + tr + i * 32) * 3072 + 2560 + cb + tc];
  __syncthreads();
#pragma unroll
  for (int i = 0; i < 2; ++i) {
    int c = tr + i * 32;
    short8 v;
#pragma unroll
    for (int j = 0; j < 8; ++j) {
      int pos = tc + j;
      int tl = (pos & ~15) | (pos & 3) | ((pos & 4) << 1) | ((pos & 8) >> 1);
      v[j] = tile[tl][c];
    }
    *(short8*)&vt[(size_t)(cb + c) * SEQ + rb + tc] = v;
  }
}

// ---------------- GEMM NT: C[m,n] = sum_k A[m,k]*B[n,k] ----------------
template <typename CT>
__global__ __launch_bounds__(256, 2) void gemm_nt(const short* __restrict__ A,
                                                  const short* __restrict__ B,
                                                  CT* __restrict__ C, int M, int N, int K) {
  __shared__ __align__(16) short As[128 * 32];
  __shared__ __align__(16) short Bs[128 * 32];
  int tid = threadIdx.x, wave = tid >> 6, lane = tid & 63;
  int lr = lane & 15, lg = lane >> 4;
  int wr = wave >> 1, wc = wave & 1;
  size_t rowA0 = (size_t)blockIdx.y * 128, colB0 = (size_t)blockIdx.x * 128;
  f32x4 acc[4][4] = {};

  for (int kt = 0; kt < K; kt += 32) {
#pragma unroll
    for (int c = 0; c < 2; ++c) {
      int chunk = wave * 2 + c;
      int row = chunk * 16 + (lane >> 2);
      int col = (lane & 3) * 8;
      gload16(A + (rowA0 + row) * (size_t)K + kt + col, &As[chunk * 512]);
      gload16(B + (colB0 + row) * (size_t)K + kt + col, &Bs[chunk * 512]);
    }
    __syncthreads();
    short8 a[4], b[4];
#pragma unroll
    for (int i = 0; i < 4; ++i) {
      a[i] = *(const short8*)&As[(wr * 64 + i * 16 + lr) * 32 + lg * 8];
      b[i] = *(const short8*)&Bs[(wc * 64 + i * 16 + lr) * 32 + lg * 8];
    }
#pragma unroll
    for (int i = 0; i < 4; ++i)
#pragma unroll
      for (int j = 0; j < 4; ++j)
        acc[i][j] = __builtin_amdgcn_mfma_f32_16x16x32_bf16(a[i], b[j], acc[i][j], 0, 0, 0);
    __syncthreads();
  }
#pragma unroll
  for (int i = 0; i < 4; ++i)
#pragma unroll
    for (int j = 0; j < 4; ++j)
#pragma unroll
      for (int r = 0; r < 4; ++r) {
        size_t row = rowA0 + wr * 64 + i * 16 + lg * 4 + r;
        size_t col = colB0 + wc * 64 + j * 16 + lr;
        if constexpr (sizeof(CT) == 2) C[row * N + col] = (CT)bf16_rne(acc[i][j][r]);
        else C[row * N + col] = acc[i][j][r];
      }
}

// ---------------- flash attention: 32x32 MFMA, swapped QK, zero-routing PV ----------
// Per wave: 32 q-rows, D=128. Block = 4 waves (128 q). KVBLK=32, dbuf, 1 barrier/iter.
// K LDS granule (dg,t): byte=(dg*32+t)*16 holds K[t][dg*8..+7]  (8 KB/buf)
// V LDS granule (tg,p): byte=(tg*128+d)*16 holds Vt'[d][tg*8..+7] (8 KB/buf, t-permuted)
// All fragment reads: 32-lane sequential 512B runs -> conflict-free (r8: 0 conflicts).
// Regs: ~76 arch + 64 acc (~140) -> 8 waves/CU; (256,2) — do NOT request 4: demand >128
// causes scratch spill (r5, r9 both measured: FETCH 0.3-1.7 GB, 2x slowdown).
__global__ __launch_bounds__(256, 2) void attn_kernel(const short* __restrict__ QKV,
                                                      const short* __restrict__ Vt,
                                                      short* __restrict__ Oat) {
  __shared__ __align__(16) short Ks[2][4096];
  __shared__ __align__(16) short Vs[2][4096];
  int tid = threadIdx.x, wave = tid >> 6, lane = tid & 63;
  int l31 = lane & 31, hi = lane >> 5;
  int h = blockIdx.y, kv = h >> 2;
  int q0 = blockIdx.x * 128 + wave * 32;

  // Q B-fragments: qf[kb] = Q[q0+l31][d = kb*16 + hi*8 + 0..7]
  short8 qf[8];
#pragma unroll
  for (int kb = 0; kb < 8; ++kb)
    qf[kb] = *(const short8*)&QKV[(size_t)(q0 + l31) * 3072 + h * 128 + kb * 16 + hi * 8];

  f32x16 oacc[4] = {};
  float m_run = -1e30f, lsum = 0.f;

  const float sc = 1.44269504089f * 0.08838834764831845f;  // log2e / sqrt(128)
  const float THR_S = 60.f;
  const short* Kbase = QKV + 2048 + kv * 128;

  auto stageK = [&](int b, int t0) {
#pragma unroll
    for (int cc = 0; cc < 2; ++cc) {
      int c = wave * 2 + cc;  // granule: dg = 2c + hi, t = l31
      gload16(Kbase + (size_t)(t0 + l31) * 3072 + c * 16 + hi * 8, &Ks[b][c * 512]);
    }
  };
  auto stageV = [&](int b, int t0) {
#pragma unroll
    for (int cc = 0; cc < 2; ++cc) {
      int c = wave * 2 + cc;  // granule: tg = c>>1, d = (c&1)*64 + lane
      int d = (c & 1) * 64 + lane;
      gload16(Vt + (size_t)(kv * 128 + d) * SEQ + t0 + (c >> 1) * 8, &Vs[b][c * 512]);
    }
  };

  stageK(0, 0);
  stageV(0, 0);
  __syncthreads();
  int buf = 0;

  for (int t0 = 0; t0 < SEQ; t0 += 32) {
    int tn = (t0 + 32 < SEQ) ? t0 + 32 : 0;
    stageK(buf ^ 1, tn);
    stageV(buf ^ 1, tn);

    // S^T = mfma(K, Q): col = q = l31; reg r -> t = (r&3)+8*(r>>2)+4*hi
    f32x16 sacc = {};
    __builtin_amdgcn_s_setprio(1);
#pragma unroll
    for (int kb = 0; kb < 8; ++kb) {
      short8 kf = *(const short8*)&Ks[buf][((kb * 2 + hi) * 32 + l31) * 8];
      sacc = __builtin_amdgcn_mfma_f32_32x32x16_bf16(kf, qf[kb], sacc, 0, 0, 0);
    }
    __builtin_amdgcn_s_setprio(0);

    // in-lane max over this lane's 16 t-values of row q=l31; rare full rescale
    float vmax = fmaxf(sacc[0], sacc[1]);
#pragma unroll
    for (int r = 2; r < 16; ++r) vmax = fmaxf(vmax, sacc[r]);
    if (__any(vmax > m_run + THR_S)) {
      float mnew = fmaxf(fmaxf(vmax, __shfl_xor(vmax, 32)), m_run);
      float corr = __builtin_amdgcn_exp2f((m_run - mnew) * sc);
      lsum *= corr;
      m_run = mnew;
#pragma unroll
      for (int nb = 0; nb < 4; ++nb) oacc[nb] *= corr;
    }

    // P = exp(S - m): fused exp + sum + pack, no p[] array, no cross-half routing
    float msc = m_run * sc;
    float ps = 0.f;
    u32 w[8];
#pragma unroll
    for (int i = 0; i < 8; ++i) {
      float p0 = __builtin_amdgcn_exp2f(sacc[2 * i] * sc - msc);
      float p1 = __builtin_amdgcn_exp2f(sacc[2 * i + 1] * sc - msc);
      ps += p0 + p1;
      asm("v_cvt_pk_bf16_f32 %0, %1, %2" : "=v"(w[i]) : "v"(p0), "v"(p1));
    }
    lsum += ps;
    short8 pa0 = __builtin_bit_cast(short8, (u32x4){w[0], w[1], w[2], w[3]});
    short8 pa1 = __builtin_bit_cast(short8, (u32x4){w[4], w[5], w[6], w[7]});

    // PV: O[q][d] += P[q][t] V[t][d]; V staged in perm16 t-order so A = own words
    __builtin_amdgcn_s_setprio(1);
#pragma unroll
    for (int nb = 0; nb < 4; ++nb) {
      short8 v0 = *(const short8*)&Vs[buf][((hi)*128 + nb * 32 + l31) * 8];
      oacc[nb] = __builtin_amdgcn_mfma_f32_32x32x16_bf16(pa0, v0, oacc[nb], 0, 0, 0);
      short8 v1 = *(const short8*)&Vs[buf][((2 + hi) * 128 + nb * 32 + l31) * 8];
      oacc[nb] = __builtin_amdgcn_mfma_f32_32x32x16_bf16(pa1, v1, oacc[nb], 0, 0, 0);
    }
    __builtin_amdgcn_s_setprio(0);

    __syncthreads();  // next buffer staged; all waves done reading buf
    buf ^= 1;
  }

  // combine l across halves, normalize, store
  lsum += __shfl_xor(lsum, 32);  // full row sum for q = l31
  float linv = 1.f / lsum;
#pragma unroll
  for (int r = 0; r < 16; ++r) {
    int qrow = (r & 3) + 8 * (r >> 2) + 4 * hi;
    float lr_ = __shfl(linv, qrow);
#pragma unroll
    for (int nb = 0; nb < 4; ++nb)
      Oat[(size_t)(q0 + qrow) * HID + h * 128 + nb * 32 + l31] = bf16_rne(oacc[nb][r] * lr_);
  }
}

extern "C" void kernel_launch(void* const* d_in, const int* in_sizes, int n_in,
                              void* d_out, int out_size, void* d_ws, size_t ws_size,
                              hipStream_t stream) {
  const float* x = (const float*)d_in[0];
  const float* Wq = (const float*)d_in[1];
  const float* Wk = (const float*)d_in[2];
  const float* Wv = (const float*)d_in[3];
  const float* Wo = (const float*)d_in[4];
  float* out = (float*)d_out;
  char* ws = (char*)d_ws;

  // workspace layout:
  short* xb = (short*)(ws);                          // [4096][2048]  16MB (later: Oat)
  short* wqkv = (short*)(ws + (16u << 20));          // [3072][2048]  12MB (later: Vt)
  short* wob = (short*)(ws + (28u << 20));           // [2048][2048]   8MB
  short* qkv = (short*)(ws + (36u << 20));           // [4096][3072]  24MB
  short* vt = wqkv;                                  // [512][4096]    4MB
  short* oat = xb;                                   // [4096][2048]  16MB

  cast_bf16<<<4096, 256, 0, stream>>>(x, xb, 1048576);
  cast_bf16<<<2048, 256, 0, stream>>>(Wq, wqkv, 524288);
  cast_bf16<<<512, 256, 0, stream>>>(Wk, wqkv + (size_t)2048 * 2048, 131072);
  cast_bf16<<<512, 256, 0, stream>>>(Wv, wqkv + (size_t)2560 * 2048, 131072);
  cast_bf16<<<2048, 256, 0, stream>>>(Wo, wob, 524288);

  // QKV = x * [Wq;Wk;Wv]^T : [4096][3072]
  gemm_nt<short><<<dim3(24, 32), 256, 0, stream>>>(xb, wqkv, qkv, 4096, 3072, 2048);
  // V^T (t-bit-swapped) for the PV step
  transpose_v<<<dim3(64, 8), 256, 0, stream>>>(qkv, vt);
  // fused flash attention: 512 blocks = 2 blocks/CU, one pass
  attn_kernel<<<dim3(32, 16), 256, 0, stream>>>(qkv, vt, oat);
  // out = Oat * Wo^T (fp32 out)
  gemm_nt<float><<<dim3(16, 32), 256, 0, stream>>>(oat, wob, out, 4096, HID, 2048);
}